// Round 17
// baseline (104.980 us; speedup 1.0000x reference)
//
#include <hip/hip_runtime.h>
#include <hip/hip_bf16.h>
#include <stdint.h>

#define TM 64        // tokens per block
#define NT 512       // threads per block (8 waves)
#define HDIM 256
#define HA 276       // H + AA
#define HAP 288      // HA padded to multiple of 32
#define ZROW 296     // LDS row stride in fp16 elems
#define AAC 20
#define GMAXC 4
#define EMAXC 10
#define NATOMC 14

// ws layout (fp16 elems): hi block [0, WS_ELEMS), residual block [WS_ELEMS, 2*WS_ELEMS)
// within each block: W1T [256][288] @0 ; W2T [256][256] @73728 ; W3T [32][256] @139264
#define W1T_OFF 0
#define W2T_OFF 73728
#define W3T_OFF 139264
#define WS_ELEMS 147456

// static LDS layout (bytes), TM=64:
//   z   @ 0      : 64*296*2 = 37888   (fp16; after GEMM3 barrier reused: Xs @0 (10752), exS @10752 (896))
//   tsS @ 37888  : 64*19*4 = 4864
// total 42752 -> 3 blocks/CU (24 waves/CU = 6 waves/SIMD)
#define Z_OFF   0
#define XS_OFF  0
#define EXS_OFF 10752
#define TSS_OFF 37888
#define SMEM_BYTES 42752

typedef __attribute__((ext_vector_type(8))) _Float16 f16x8;
typedef __attribute__((ext_vector_type(4))) _Float16 f16x4;
typedef __attribute__((ext_vector_type(4))) float f32x4;

__device__ __forceinline__ float silu_f(float x) {
    return x * (1.0f / (1.0f + __expf(-x)));
}

__device__ __forceinline__ float tanh_fast(float x) {
    float e = __expf(2.0f * x);
    return 1.0f - 2.0f / (e + 1.0f);
}

// ---------------- prep: fp32 weights -> transposed fp16 hi + fp16 residual in ws ----------------
template <bool SPLIT>
__global__ __launch_bounds__(256) void prep_weights(
    const float* __restrict__ W1, const float* __restrict__ W2,
    const float* __restrict__ Wt, const float* __restrict__ Ws,
    _Float16* __restrict__ ws)
{
    int idx = blockIdx.x * 256 + threadIdx.x;
    if (idx >= WS_ELEMS) return;
    float v;
    if (idx < W2T_OFF) {                       // W1T[n][k], k padded 276->288
        int n = idx / HAP, k = idx - n * HAP;
        v = (k < HA) ? W1[(size_t)k * HDIM + n] : 0.0f;
    } else if (idx < W3T_OFF) {                // W2T[n][k]
        int i = idx - W2T_OFF;
        int n = i / HDIM, k = i - n * HDIM;
        v = W2[(size_t)k * HDIM + n];
    } else {                                   // W3T[n][k]: n<4 Wt, 4<=n<18 Ws, else 0
        int i = idx - W3T_OFF;
        int n = i / HDIM, k = i - n * HDIM;
        v = (n < GMAXC) ? Wt[(size_t)k * GMAXC + n]
          : (n < GMAXC + NATOMC) ? Ws[(size_t)k * NATOMC + (n - GMAXC)]
          : 0.0f;
    }
    _Float16 hi = (_Float16)v;
    ws[idx] = hi;
    if (SPLIT) ws[WS_ELEMS + idx] = (_Float16)(v - (float)hi);   // |res| <= 2^-11 |v|
}

// ---------------- fused main kernel ----------------
template <bool SPLIT>
__global__ __launch_bounds__(NT, 6) void fused_refiner(
    const float* __restrict__ h,        // (BN, 256)
    const float* __restrict__ probs,    // (BN, 20)
    const float* __restrict__ X,        // (BN, 14, 3)
    const _Float16* __restrict__ ws,    // prepped fp16 weights (hi[,res])
    const float* __restrict__ b1,       // (256)
    const float* __restrict__ b2,       // (256)
    const float* __restrict__ bt,       // (4)
    const float* __restrict__ bs,       // (14)
    const int* __restrict__ exists,     // (BN, 14) bool as int32
    const int* __restrict__ top_idx,    // (BN)
    const int* __restrict__ TA,         // (20, 4, 2)
    const int* __restrict__ AI,         // (20, 4, 10)
    const int* __restrict__ AM,         // (20, 4, 10) bool as int32
    const int* __restrict__ GC,         // (20)
    const int* __restrict__ SM,         // (20, 14) bool as int32
    const int* __restrict__ SP,         // (20, 14)
    float* __restrict__ out)            // (BN, 14, 3)
{
    __shared__ __align__(16) unsigned char smem[SMEM_BYTES];
    _Float16 (*z)[ZROW]    = (_Float16 (*)[ZROW])(smem + Z_OFF);
    float (*tsS)[19]       = (float (*)[19])(smem + TSS_OFF);
    float (*Xs)[NATOMC][3] = (float (*)[NATOMC][3])(smem + XS_OFF);   // valid after GEMM3 barrier
    uint8_t (*exS)[NATOMC] = (uint8_t (*)[NATOMC])(smem + EXS_OFF);   // valid after GEMM3 barrier

    const int tid  = threadIdx.x;
    const int tok0 = blockIdx.x * TM;

    const int wv   = tid >> 6;     // wave 0..7
    const int ln   = tid & 63;
    const int ln16 = ln & 15;
    const int kg   = ln >> 4;      // k-group 0..3
    const int nc0  = wv * 32;      // this wave's output-column base (GEMM1/2)

    // ---------------- Phase 0: stage z = [h | probs] as fp16 ----------------
    {
        const float4* h4 = reinterpret_cast<const float4*>(h + (size_t)tok0 * HDIM);
        for (int idx = tid; idx < TM * (HDIM / 4); idx += NT) {
            int t  = idx >> 6;
            int kq = idx & 63;
            float4 v = h4[(size_t)t * (HDIM / 4) + kq];
            f16x4 s;
            s.x = (_Float16)v.x; s.y = (_Float16)v.y;
            s.z = (_Float16)v.z; s.w = (_Float16)v.w;
            *reinterpret_cast<f16x4*>(&z[t][kq * 4]) = s;
        }
        for (int idx = tid; idx < TM * AAC; idx += NT) {
            int t = idx / AAC;
            int p = idx - t * AAC;
            z[t][HDIM + p] = (_Float16)probs[(size_t)(tok0 + t) * AAC + p];
        }
        for (int idx = tid; idx < TM * (ZROW - HA); idx += NT) {   // zero pad [276,296)
            int t = idx / (ZROW - HA);
            int p = idx - t * (ZROW - HA);
            z[t][HA + p] = (_Float16)0.0f;
        }
    }
    __syncthreads();

    const _Float16* Wh = ws;
    const _Float16* Wl = ws + WS_ELEMS;

    // ---------------- GEMM1: z1 = silu(z @ W1 + b1), K = 288, M = 64/wave ----------------
    // fp16 activations x (W16 + res16) 2-term; bias folded; 1-deep weight prefetch.
    {
        f32x4 acc[4][2];
        {
            const float bb0 = b1[nc0 + ln16];
            const float bb1 = b1[nc0 + 16 + ln16];
            #pragma unroll
            for (int m = 0; m < 4; ++m) {
                acc[m][0] = (f32x4){bb0, bb0, bb0, bb0};
                acc[m][1] = (f32x4){bb1, bb1, bb1, bb1};
            }
        }

        const size_t wbase = (size_t)(nc0 + ln16) * HAP + kg * 8 + W1T_OFF;
        f16x8 nbh0 = *reinterpret_cast<const f16x8*>(Wh + wbase);
        f16x8 nbh1 = *reinterpret_cast<const f16x8*>(Wh + wbase + 16 * HAP);
        f16x8 nbl0 = {}, nbl1 = {};
        if (SPLIT) {
            nbl0 = *reinterpret_cast<const f16x8*>(Wl + wbase);
            nbl1 = *reinterpret_cast<const f16x8*>(Wl + wbase + 16 * HAP);
        }
        #pragma unroll
        for (int kc = 0; kc < 9; ++kc) {
            const f16x8 bh0 = nbh0, bh1 = nbh1, bl0 = nbl0, bl1 = nbl1;
            if (kc + 1 < 9) {
                const size_t wn = wbase + (size_t)(kc + 1) * 32;
                nbh0 = *reinterpret_cast<const f16x8*>(Wh + wn);
                nbh1 = *reinterpret_cast<const f16x8*>(Wh + wn + 16 * HAP);
                if (SPLIT) {
                    nbl0 = *reinterpret_cast<const f16x8*>(Wl + wn);
                    nbl1 = *reinterpret_cast<const f16x8*>(Wl + wn + 16 * HAP);
                }
            }
            const int kk = kc * 32 + kg * 8;
            f16x8 a[4];
            #pragma unroll
            for (int m = 0; m < 4; ++m)
                a[m] = *reinterpret_cast<const f16x8*>(&z[m * 16 + ln16][kk]);
            // n = 0 block
            #pragma unroll
            for (int m = 0; m < 4; ++m)
                acc[m][0] = __builtin_amdgcn_mfma_f32_16x16x32_f16(a[m], bh0, acc[m][0], 0, 0, 0);
            if (SPLIT) {
                #pragma unroll
                for (int m = 0; m < 4; ++m)
                    acc[m][0] = __builtin_amdgcn_mfma_f32_16x16x32_f16(a[m], bl0, acc[m][0], 0, 0, 0);
            }
            // n = 1 block
            #pragma unroll
            for (int m = 0; m < 4; ++m)
                acc[m][1] = __builtin_amdgcn_mfma_f32_16x16x32_f16(a[m], bh1, acc[m][1], 0, 0, 0);
            if (SPLIT) {
                #pragma unroll
                for (int m = 0; m < 4; ++m)
                    acc[m][1] = __builtin_amdgcn_mfma_f32_16x16x32_f16(a[m], bl1, acc[m][1], 0, 0, 0);
            }
        }
        __syncthreads();   // all reads of z done before overwrite
        #pragma unroll
        for (int n = 0; n < 2; ++n) {
            const int col = nc0 + n * 16 + ln16;
            #pragma unroll
            for (int m = 0; m < 4; ++m) {
                #pragma unroll
                for (int r = 0; r < 4; ++r) {
                    const int row = m * 16 + kg * 4 + r;
                    z[row][col] = (_Float16)silu_f(acc[m][n][r]);
                }
            }
        }
    }
    __syncthreads();

    // ---------------- GEMM2: z2 = silu(z1 @ W2 + b2), K = 256 ----------------
    {
        f32x4 acc[4][2];
        {
            const float bb0 = b2[nc0 + ln16];
            const float bb1 = b2[nc0 + 16 + ln16];
            #pragma unroll
            for (int m = 0; m < 4; ++m) {
                acc[m][0] = (f32x4){bb0, bb0, bb0, bb0};
                acc[m][1] = (f32x4){bb1, bb1, bb1, bb1};
            }
        }

        const size_t wbase = (size_t)(nc0 + ln16) * HDIM + kg * 8 + W2T_OFF;
        f16x8 nbh0 = *reinterpret_cast<const f16x8*>(Wh + wbase);
        f16x8 nbh1 = *reinterpret_cast<const f16x8*>(Wh + wbase + 16 * HDIM);
        f16x8 nbl0 = {}, nbl1 = {};
        if (SPLIT) {
            nbl0 = *reinterpret_cast<const f16x8*>(Wl + wbase);
            nbl1 = *reinterpret_cast<const f16x8*>(Wl + wbase + 16 * HDIM);
        }
        #pragma unroll
        for (int kc = 0; kc < 8; ++kc) {
            const f16x8 bh0 = nbh0, bh1 = nbh1, bl0 = nbl0, bl1 = nbl1;
            if (kc + 1 < 8) {
                const size_t wn = wbase + (size_t)(kc + 1) * 32;
                nbh0 = *reinterpret_cast<const f16x8*>(Wh + wn);
                nbh1 = *reinterpret_cast<const f16x8*>(Wh + wn + 16 * HDIM);
                if (SPLIT) {
                    nbl0 = *reinterpret_cast<const f16x8*>(Wl + wn);
                    nbl1 = *reinterpret_cast<const f16x8*>(Wl + wn + 16 * HDIM);
                }
            }
            const int kk = kc * 32 + kg * 8;
            f16x8 a[4];
            #pragma unroll
            for (int m = 0; m < 4; ++m)
                a[m] = *reinterpret_cast<const f16x8*>(&z[m * 16 + ln16][kk]);
            // n = 0 block
            #pragma unroll
            for (int m = 0; m < 4; ++m)
                acc[m][0] = __builtin_amdgcn_mfma_f32_16x16x32_f16(a[m], bh0, acc[m][0], 0, 0, 0);
            if (SPLIT) {
                #pragma unroll
                for (int m = 0; m < 4; ++m)
                    acc[m][0] = __builtin_amdgcn_mfma_f32_16x16x32_f16(a[m], bl0, acc[m][0], 0, 0, 0);
            }
            // n = 1 block
            #pragma unroll
            for (int m = 0; m < 4; ++m)
                acc[m][1] = __builtin_amdgcn_mfma_f32_16x16x32_f16(a[m], bh1, acc[m][1], 0, 0, 0);
            if (SPLIT) {
                #pragma unroll
                for (int m = 0; m < 4; ++m)
                    acc[m][1] = __builtin_amdgcn_mfma_f32_16x16x32_f16(a[m], bl1, acc[m][1], 0, 0, 0);
            }
        }
        __syncthreads();   // all reads of z1 done before overwrite
        #pragma unroll
        for (int n = 0; n < 2; ++n) {
            const int col = nc0 + n * 16 + ln16;
            #pragma unroll
            for (int m = 0; m < 4; ++m) {
                #pragma unroll
                for (int r = 0; r < 4; ++r) {
                    const int row = m * 16 + kg * 4 + r;
                    z[row][col] = (_Float16)silu_f(acc[m][n][r]);
                }
            }
        }
    }
    __syncthreads();

    // ---------------- GEMM3 (all 8 waves): [dchi|sraw] = tanh(z2 @ [Wt|Ws] + b) ----------------
    {
        const int m3 = wv & 3;       // token quarter (16 tokens)
        const int n3 = wv >> 2;      // output-col half
        const int o  = n3 * 16 + ln16;
        const float bias3 = (o < GMAXC) ? bt[o]
                          : (o < GMAXC + NATOMC) ? bs[o - GMAXC] : 0.0f;
        f32x4 acc = (f32x4){bias3, bias3, bias3, bias3};
        const size_t wbase = (size_t)(n3 * 16 + ln16) * HDIM + kg * 8 + W3T_OFF;
        #pragma unroll
        for (int kc = 0; kc < 8; ++kc) {
            const int kk = kc * 32 + kg * 8;
            f16x8 a = *reinterpret_cast<const f16x8*>(&z[m3 * 16 + ln16][kk]);
            const size_t wo = wbase + kc * 32;
            f16x8 bh = *reinterpret_cast<const f16x8*>(Wh + wo);
            acc = __builtin_amdgcn_mfma_f32_16x16x32_f16(a, bh, acc, 0, 0, 0);
            if (SPLIT) {
                f16x8 bl = *reinterpret_cast<const f16x8*>(Wl + wo);
                acc = __builtin_amdgcn_mfma_f32_16x16x32_f16(a, bl, acc, 0, 0, 0);
            }
        }
        if (o < GMAXC + NATOMC) {
            #pragma unroll
            for (int r = 0; r < 4; ++r) {
                const int tok = m3 * 16 + kg * 4 + r;
                float val = tanh_fast(acc[r]);
                if (o < GMAXC) val *= 0.5f;
                tsS[tok][o] = val;
            }
        }
    }
    __syncthreads();   // z reads complete; tsS published; z region now dead

    // ---------------- stage X / exists wave-locally (wave w owns tokens 8w..8w+7) ----------------
    // Disjoint Xs/exS slabs per wave (aliasing dead z region); FK below same-wave -> NO barrier.
    {
        const int tbase = wv * 8;
        const float* Xg = X + (size_t)(tok0 + tbase) * NATOMC * 3;
        float* Xsf = &Xs[tbase][0][0];
        #pragma unroll
        for (int i = 0; i < 6; ++i) {
            const int idx = ln + i * 64;
            if (idx < 8 * NATOMC * 3) Xsf[idx] = Xg[idx];
        }
        const int* Eg = exists + (size_t)(tok0 + tbase) * NATOMC;
        uint8_t* exf = &exS[tbase][0];
        #pragma unroll
        for (int i = 0; i < 2; ++i) {
            const int idx = ln + i * 64;
            if (idx < 8 * NATOMC) exf[idx] = (uint8_t)(Eg[idx] != 0);
        }
    }
    // (no barrier: FK for wave w reads only wave-w slabs; same-wave LDS order is program order)

    // ---------------- FK: wave-local (8 tokens/wave, 8 lanes/token), NO barriers ----------------
    {
        const int t_loc = ln >> 3;              // 0..7
        const int r     = ln & 7;               // worker within token
        const int t     = wv * 8 + t_loc;       // token within tile
        const int a     = top_idx[tok0 + t];

        for (int gi = 0; gi < GMAXC; ++gi) {
            const int u  = TA[a * 8 + gi * 2 + 0];
            const int v  = TA[a * 8 + gi * 2 + 1];
            const int gc = GC[a];
            const bool axis_ok = (u >= 0) && (v >= 0) && (gi < gc);
            const int iu = u > 0 ? u : 0;
            const int iv = v > 0 ? v : 0;
            const float pux = Xs[t][iu][0], puy = Xs[t][iu][1], puz = Xs[t][iu][2];
            float ax = Xs[t][iv][0] - pux;
            float ay = Xs[t][iv][1] - puy;
            float az = Xs[t][iv][2] - puz;
            const float nrm = sqrtf(ax * ax + ay * ay + az * az);
            const float inv = 1.0f / fmaxf(nrm, 1e-8f);
            const float nx = ax * inv, ny = ay * inv, nz = az * inv;
            const float ang = axis_ok ? tsS[t][gi] : 0.0f;
            float sn, cs;
            __sincosf(ang, &sn, &cs);
            const float omc = 1.0f - cs;

            float newp[2][3];
            int   cidx[2];
            bool  wf[2];
            #pragma unroll
            for (int q = 0; q < 2; ++q) {
                const int e = r + q * 8;
                wf[q] = false; cidx[q] = 0;
                if (e < EMAXC) {
                    const int craw = AI[a * 40 + gi * 10 + e];
                    const int c = craw > 0 ? craw : 0;
                    const bool m = AM[a * 40 + gi * 10 + e] != 0;
                    const float vx = Xs[t][c][0] - pux;
                    const float vy = Xs[t][c][1] - puy;
                    const float vz = Xs[t][c][2] - puz;
                    const float dt  = vx * nx + vy * ny + vz * nz;
                    const float crx = ny * vz - nz * vy;
                    const float cry = nz * vx - nx * vz;
                    const float crz = nx * vy - ny * vx;
                    newp[q][0] = pux + vx * cs + crx * sn + nx * dt * omc;
                    newp[q][1] = puy + vy * cs + cry * sn + ny * dt * omc;
                    newp[q][2] = puz + vz * cs + crz * sn + nz * dt * omc;
                    const bool exc = exS[t][c] != 0;
                    wf[q] = m && exc;
                    cidx[q] = c;
                }
            }
            // same-wave lockstep: both gathers retire before the stores below issue
            #pragma unroll
            for (int q = 0; q < 2; ++q) {
                if (wf[q]) {
                    Xs[t][cidx[q]][0] = newp[q][0];
                    Xs[t][cidx[q]][1] = newp[q][1];
                    Xs[t][cidx[q]][2] = newp[q][2];
                }
            }
        }

        // scaling stage (reads post-torsion Xs of own token only — same wave)
        #pragma unroll
        for (int q = 0; q < 2; ++q) {
            const int e = r + q * 8;
            if (e < NATOMC) {
                const int praw = SP[a * 14 + e];
                const int p = praw > 0 ? praw : 0;
                const float ppx = Xs[t][p][0], ppy = Xs[t][p][1], ppz = Xs[t][p][2];
                const float vx = Xs[t][e][0] - ppx;
                const float vy = Xs[t][e][1] - ppy;
                const float vz = Xs[t][e][2] - ppz;
                const float sr = tsS[t][GMAXC + e];
                const float se = fminf(fmaxf(sr, -1.f), 1.f) * 0.1f;
                const float f = 1.0f + se;
                const bool w = (SM[a * 14 + e] != 0) && (exS[t][e] != 0) && (exS[t][p] != 0);
                const float ox = w ? (ppx + vx * f) : Xs[t][e][0];
                const float oy = w ? (ppy + vy * f) : Xs[t][e][1];
                const float oz = w ? (ppz + vz * f) : Xs[t][e][2];
                const size_t ob = ((size_t)(tok0 + t) * NATOMC + e) * 3;
                out[ob + 0] = ox;
                out[ob + 1] = oy;
                out[ob + 2] = oz;
            }
        }
    }
}

extern "C" void kernel_launch(void* const* d_in, const int* in_sizes, int n_in,
                              void* d_out, int out_size, void* d_ws, size_t ws_size,
                              hipStream_t stream) {
    const float* h      = (const float*)d_in[0];
    const float* probs  = (const float*)d_in[1];
    const float* X      = (const float*)d_in[2];
    const float* W1     = (const float*)d_in[3];
    const float* b1     = (const float*)d_in[4];
    const float* W2     = (const float*)d_in[5];
    const float* b2     = (const float*)d_in[6];
    const float* Wt     = (const float*)d_in[7];
    const float* bt     = (const float*)d_in[8];
    const float* Ws     = (const float*)d_in[9];
    const float* bs     = (const float*)d_in[10];
    const int*   exists = (const int*)d_in[11];
    const int*   tidx   = (const int*)d_in[12];
    const int*   TA     = (const int*)d_in[13];
    const int*   AI     = (const int*)d_in[14];
    const int*   AM     = (const int*)d_in[15];
    const int*   GC     = (const int*)d_in[16];
    const int*   SM     = (const int*)d_in[17];
    const int*   SP     = (const int*)d_in[18];
    float*       out    = (float*)d_out;
    _Float16*    ws     = (_Float16*)d_ws;

    const int BN = in_sizes[12];          // B * N = 65536
    const int grid = BN / TM;             // 1024
    const size_t need_split = (size_t)2 * WS_ELEMS * sizeof(_Float16);

    if (ws_size >= need_split) {
        prep_weights<true><<<(WS_ELEMS + 255) / 256, 256, 0, stream>>>(W1, W2, Wt, Ws, ws);
        fused_refiner<true><<<grid, NT, 0, stream>>>(h, probs, X, ws, b1, b2, bt, bs,
                                                     exists, tidx, TA, AI, AM, GC, SM, SP, out);
    } else {
        prep_weights<false><<<(WS_ELEMS + 255) / 256, 256, 0, stream>>>(W1, W2, Wt, Ws, ws);
        fused_refiner<false><<<grid, NT, 0, stream>>>(h, probs, X, ws, b1, b2, bt, bs,
                                                      exists, tidx, TA, AI, AM, GC, SM, SP, out);
    }
}

// Round 18
// 100.836 us; speedup vs baseline: 1.0411x; 1.0411x over previous
//
#include <hip/hip_runtime.h>
#include <hip/hip_bf16.h>
#include <stdint.h>

#define TM 64        // tokens per block
#define NT 512       // threads per block (8 waves)
#define HDIM 256
#define HA 276       // H + AA
#define HAP 288      // HA padded to multiple of 32
#define ZROW 296     // LDS row stride in bf16 elems (16B-aligned rows)
#define AAC 20
#define GMAXC 4
#define EMAXC 10
#define NATOMC 14

// ws layout (bf16 elems): hi block [0, WS_ELEMS), lo block [WS_ELEMS, 2*WS_ELEMS)
// within each block: W1T [256][288] @0 ; W2T [256][256] @73728 ; W3T [32][256] @139264
#define W1T_OFF 0
#define W2T_OFF 73728
#define W3T_OFF 139264
#define WS_ELEMS 147456

// static LDS layout (bytes), TM=64:
//   zh  @ 0      : 64*296*2 = 37888
//   zl  @ 37888  : 37888   (after GEMM3 barrier: reused for Xs @37888 (10752) + exS @48640 (896))
//   tsS @ 75776  : 64*19*4 = 4864
// total 80640 -> 2 blocks/CU
#define ZH_OFF  0
#define ZL_OFF  37888
#define XS_OFF  37888
#define EXS_OFF 48640
#define TSS_OFF 75776
#define SMEM_BYTES 80640

typedef __attribute__((ext_vector_type(8))) short bf16x8;
typedef __attribute__((ext_vector_type(4))) short short4v;
typedef __attribute__((ext_vector_type(4))) float f32x4;

__device__ __forceinline__ float silu_f(float x) {
    return x * (1.0f / (1.0f + __expf(-x)));
}

__device__ __forceinline__ float tanh_fast(float x) {
    float e = __expf(2.0f * x);
    return 1.0f - 2.0f / (e + 1.0f);
}

__device__ __forceinline__ unsigned short f2bf(float f) {
    union { float f; unsigned int u; } x; x.f = f;
    unsigned int r = x.u + 0x7fffu + ((x.u >> 16) & 1u);   // RTNE (prep kernel only)
    return (unsigned short)(r >> 16);
}

__device__ __forceinline__ unsigned short f2bf_trunc(float f) {
    union { float f; unsigned int u; } x; x.f = f;
    return (unsigned short)(x.u >> 16);                    // round-toward-zero (1 op)
}

__device__ __forceinline__ float bf2f(unsigned short s) {
    union { unsigned int u; float f; } x; x.u = ((unsigned int)s) << 16;
    return x.f;
}

// ---------------- prep: fp32 weights -> transposed bf16 hi(+lo) in ws ----------------
template <bool SPLIT>
__global__ __launch_bounds__(256) void prep_weights(
    const float* __restrict__ W1, const float* __restrict__ W2,
    const float* __restrict__ Wt, const float* __restrict__ Ws,
    unsigned short* __restrict__ ws)
{
    int idx = blockIdx.x * 256 + threadIdx.x;
    if (idx >= WS_ELEMS) return;
    float v;
    if (idx < W2T_OFF) {                       // W1T[n][k], k padded 276->288
        int n = idx / HAP, k = idx - n * HAP;
        v = (k < HA) ? W1[(size_t)k * HDIM + n] : 0.0f;
    } else if (idx < W3T_OFF) {                // W2T[n][k]
        int i = idx - W2T_OFF;
        int n = i / HDIM, k = i - n * HDIM;
        v = W2[(size_t)k * HDIM + n];
    } else {                                   // W3T[n][k]: n<4 Wt, 4<=n<18 Ws, else 0
        int i = idx - W3T_OFF;
        int n = i / HDIM, k = i - n * HDIM;
        v = (n < GMAXC) ? Wt[(size_t)k * GMAXC + n]
          : (n < GMAXC + NATOMC) ? Ws[(size_t)k * NATOMC + (n - GMAXC)]
          : 0.0f;
    }
    unsigned short hi = f2bf(v);
    ws[idx] = hi;
    if (SPLIT) ws[WS_ELEMS + idx] = f2bf(v - bf2f(hi));
}

// ---------------- fused main kernel ----------------
template <bool SPLIT>
__global__ __launch_bounds__(NT, 4) void fused_refiner(
    const float* __restrict__ h,        // (BN, 256)
    const float* __restrict__ probs,    // (BN, 20)
    const float* __restrict__ X,        // (BN, 14, 3)
    const unsigned short* __restrict__ ws,  // prepped bf16 weights (hi[,lo])
    const float* __restrict__ b1,       // (256)
    const float* __restrict__ b2,       // (256)
    const float* __restrict__ bt,       // (4)
    const float* __restrict__ bs,       // (14)
    const int* __restrict__ exists,     // (BN, 14) bool as int32
    const int* __restrict__ top_idx,    // (BN)
    const int* __restrict__ TA,         // (20, 4, 2)
    const int* __restrict__ AI,         // (20, 4, 10)
    const int* __restrict__ AM,         // (20, 4, 10) bool as int32
    const int* __restrict__ GC,         // (20)
    const int* __restrict__ SM,         // (20, 14) bool as int32
    const int* __restrict__ SP,         // (20, 14)
    float* __restrict__ out)            // (BN, 14, 3)
{
    __shared__ __align__(16) unsigned char smem[SMEM_BYTES];
    unsigned short (*zh)[ZROW] = (unsigned short (*)[ZROW])(smem + ZH_OFF);
    unsigned short (*zl)[ZROW] = (unsigned short (*)[ZROW])(smem + ZL_OFF);
    float (*tsS)[19]           = (float (*)[19])(smem + TSS_OFF);
    float (*Xs)[NATOMC][3]     = (float (*)[NATOMC][3])(smem + XS_OFF);   // valid after GEMM3 barrier
    uint8_t (*exS)[NATOMC]     = (uint8_t (*)[NATOMC])(smem + EXS_OFF);   // valid after GEMM3 barrier

    const int tid  = threadIdx.x;
    const int tok0 = blockIdx.x * TM;

    const int wv   = tid >> 6;     // wave 0..7
    const int ln   = tid & 63;
    const int ln16 = ln & 15;
    const int kg   = ln >> 4;      // k-group 0..3
    const int nc0  = wv * 32;      // this wave's output-column base (GEMM1/2)

    // ---------------- Phase 0: stage z = [h | probs] as hi/lo bf16 (trunc split) ----------------
    {
        const float4* h4 = reinterpret_cast<const float4*>(h + (size_t)tok0 * HDIM);
        for (int idx = tid; idx < TM * (HDIM / 4); idx += NT) {
            int t  = idx >> 6;
            int kq = idx & 63;
            float4 v = h4[(size_t)t * (HDIM / 4) + kq];
            short4v sh, sl;
            unsigned short a;
            a = f2bf_trunc(v.x); sh.x = (short)a; sl.x = (short)f2bf_trunc(v.x - bf2f(a));
            a = f2bf_trunc(v.y); sh.y = (short)a; sl.y = (short)f2bf_trunc(v.y - bf2f(a));
            a = f2bf_trunc(v.z); sh.z = (short)a; sl.z = (short)f2bf_trunc(v.z - bf2f(a));
            a = f2bf_trunc(v.w); sh.w = (short)a; sl.w = (short)f2bf_trunc(v.w - bf2f(a));
            *reinterpret_cast<short4v*>(&zh[t][kq * 4]) = sh;
            *reinterpret_cast<short4v*>(&zl[t][kq * 4]) = sl;
        }
        for (int idx = tid; idx < TM * AAC; idx += NT) {
            int t = idx / AAC;
            int p = idx - t * AAC;
            float v = probs[(size_t)(tok0 + t) * AAC + p];
            unsigned short a = f2bf_trunc(v);
            zh[t][HDIM + p] = a;
            zl[t][HDIM + p] = f2bf_trunc(v - bf2f(a));
        }
        for (int idx = tid; idx < TM * (ZROW - HA); idx += NT) {   // zero pad [276,296)
            int t = idx / (ZROW - HA);
            int p = idx - t * (ZROW - HA);
            zh[t][HA + p] = 0;
            zl[t][HA + p] = 0;
        }
    }
    __syncthreads();

    const unsigned short* Wh = ws;
    const unsigned short* Wl = ws + WS_ELEMS;

    // ---------------- GEMM1: z1 = silu(z @ W1 + b1), K = 288, M = 64/wave ----------------
    // Round-10 structure; bias folded into accumulator init; 1-deep weight prefetch.
    {
        f32x4 acc[4][2];
        {
            const float bb0 = b1[nc0 + ln16];
            const float bb1 = b1[nc0 + 16 + ln16];
            #pragma unroll
            for (int m = 0; m < 4; ++m) {
                acc[m][0] = (f32x4){bb0, bb0, bb0, bb0};
                acc[m][1] = (f32x4){bb1, bb1, bb1, bb1};
            }
        }

        const size_t wbase = (size_t)(nc0 + ln16) * HAP + kg * 8 + W1T_OFF;
        bf16x8 nbh0 = *reinterpret_cast<const bf16x8*>(Wh + wbase);
        bf16x8 nbh1 = *reinterpret_cast<const bf16x8*>(Wh + wbase + 16 * HAP);
        bf16x8 nbl0 = {}, nbl1 = {};
        if (SPLIT) {
            nbl0 = *reinterpret_cast<const bf16x8*>(Wl + wbase);
            nbl1 = *reinterpret_cast<const bf16x8*>(Wl + wbase + 16 * HAP);
        }
        #pragma unroll
        for (int kc = 0; kc < 9; ++kc) {
            const bf16x8 bh0 = nbh0, bh1 = nbh1, bl0 = nbl0, bl1 = nbl1;
            if (kc + 1 < 9) {
                const size_t wn = wbase + (size_t)(kc + 1) * 32;
                nbh0 = *reinterpret_cast<const bf16x8*>(Wh + wn);
                nbh1 = *reinterpret_cast<const bf16x8*>(Wh + wn + 16 * HAP);
                if (SPLIT) {
                    nbl0 = *reinterpret_cast<const bf16x8*>(Wl + wn);
                    nbl1 = *reinterpret_cast<const bf16x8*>(Wl + wn + 16 * HAP);
                }
            }
            const int kk = kc * 32 + kg * 8;
            bf16x8 ah[4], al[4];
            #pragma unroll
            for (int m = 0; m < 4; ++m) {
                ah[m] = *reinterpret_cast<const bf16x8*>(&zh[m * 16 + ln16][kk]);
                al[m] = *reinterpret_cast<const bf16x8*>(&zl[m * 16 + ln16][kk]);
            }
            // n = 0 block (round-10 order)
            #pragma unroll
            for (int m = 0; m < 4; ++m)
                acc[m][0] = __builtin_amdgcn_mfma_f32_16x16x32_bf16(ah[m], bh0, acc[m][0], 0, 0, 0);
            #pragma unroll
            for (int m = 0; m < 4; ++m)
                acc[m][0] = __builtin_amdgcn_mfma_f32_16x16x32_bf16(al[m], bh0, acc[m][0], 0, 0, 0);
            if (SPLIT) {
                #pragma unroll
                for (int m = 0; m < 4; ++m)
                    acc[m][0] = __builtin_amdgcn_mfma_f32_16x16x32_bf16(ah[m], bl0, acc[m][0], 0, 0, 0);
            }
            // n = 1 block
            #pragma unroll
            for (int m = 0; m < 4; ++m)
                acc[m][1] = __builtin_amdgcn_mfma_f32_16x16x32_bf16(ah[m], bh1, acc[m][1], 0, 0, 0);
            #pragma unroll
            for (int m = 0; m < 4; ++m)
                acc[m][1] = __builtin_amdgcn_mfma_f32_16x16x32_bf16(al[m], bh1, acc[m][1], 0, 0, 0);
            if (SPLIT) {
                #pragma unroll
                for (int m = 0; m < 4; ++m)
                    acc[m][1] = __builtin_amdgcn_mfma_f32_16x16x32_bf16(ah[m], bl1, acc[m][1], 0, 0, 0);
            }
        }
        __syncthreads();   // all reads of z done before overwrite
        #pragma unroll
        for (int n = 0; n < 2; ++n) {
            const int col = nc0 + n * 16 + ln16;
            #pragma unroll
            for (int m = 0; m < 4; ++m) {
                #pragma unroll
                for (int r = 0; r < 4; ++r) {
                    const int row = m * 16 + kg * 4 + r;
                    float val = silu_f(acc[m][n][r]);
                    unsigned short hi = f2bf_trunc(val);
                    zh[row][col] = hi;
                    zl[row][col] = f2bf_trunc(val - bf2f(hi));
                }
            }
        }
    }
    __syncthreads();

    // ---------------- GEMM2: z2 = silu(z1 @ W2 + b2), K = 256 ----------------
    {
        f32x4 acc[4][2];
        {
            const float bb0 = b2[nc0 + ln16];
            const float bb1 = b2[nc0 + 16 + ln16];
            #pragma unroll
            for (int m = 0; m < 4; ++m) {
                acc[m][0] = (f32x4){bb0, bb0, bb0, bb0};
                acc[m][1] = (f32x4){bb1, bb1, bb1, bb1};
            }
        }

        const size_t wbase = (size_t)(nc0 + ln16) * HDIM + kg * 8 + W2T_OFF;
        bf16x8 nbh0 = *reinterpret_cast<const bf16x8*>(Wh + wbase);
        bf16x8 nbh1 = *reinterpret_cast<const bf16x8*>(Wh + wbase + 16 * HDIM);
        bf16x8 nbl0 = {}, nbl1 = {};
        if (SPLIT) {
            nbl0 = *reinterpret_cast<const bf16x8*>(Wl + wbase);
            nbl1 = *reinterpret_cast<const bf16x8*>(Wl + wbase + 16 * HDIM);
        }
        #pragma unroll
        for (int kc = 0; kc < 8; ++kc) {
            const bf16x8 bh0 = nbh0, bh1 = nbh1, bl0 = nbl0, bl1 = nbl1;
            if (kc + 1 < 8) {
                const size_t wn = wbase + (size_t)(kc + 1) * 32;
                nbh0 = *reinterpret_cast<const bf16x8*>(Wh + wn);
                nbh1 = *reinterpret_cast<const bf16x8*>(Wh + wn + 16 * HDIM);
                if (SPLIT) {
                    nbl0 = *reinterpret_cast<const bf16x8*>(Wl + wn);
                    nbl1 = *reinterpret_cast<const bf16x8*>(Wl + wn + 16 * HDIM);
                }
            }
            const int kk = kc * 32 + kg * 8;
            bf16x8 ah[4], al[4];
            #pragma unroll
            for (int m = 0; m < 4; ++m) {
                ah[m] = *reinterpret_cast<const bf16x8*>(&zh[m * 16 + ln16][kk]);
                al[m] = *reinterpret_cast<const bf16x8*>(&zl[m * 16 + ln16][kk]);
            }
            // n = 0 block (round-10 order)
            #pragma unroll
            for (int m = 0; m < 4; ++m)
                acc[m][0] = __builtin_amdgcn_mfma_f32_16x16x32_bf16(ah[m], bh0, acc[m][0], 0, 0, 0);
            #pragma unroll
            for (int m = 0; m < 4; ++m)
                acc[m][0] = __builtin_amdgcn_mfma_f32_16x16x32_bf16(al[m], bh0, acc[m][0], 0, 0, 0);
            if (SPLIT) {
                #pragma unroll
                for (int m = 0; m < 4; ++m)
                    acc[m][0] = __builtin_amdgcn_mfma_f32_16x16x32_bf16(ah[m], bl0, acc[m][0], 0, 0, 0);
            }
            // n = 1 block
            #pragma unroll
            for (int m = 0; m < 4; ++m)
                acc[m][1] = __builtin_amdgcn_mfma_f32_16x16x32_bf16(ah[m], bh1, acc[m][1], 0, 0, 0);
            #pragma unroll
            for (int m = 0; m < 4; ++m)
                acc[m][1] = __builtin_amdgcn_mfma_f32_16x16x32_bf16(al[m], bh1, acc[m][1], 0, 0, 0);
            if (SPLIT) {
                #pragma unroll
                for (int m = 0; m < 4; ++m)
                    acc[m][1] = __builtin_amdgcn_mfma_f32_16x16x32_bf16(ah[m], bl1, acc[m][1], 0, 0, 0);
            }
        }
        __syncthreads();   // all reads of z1 done before overwrite
        #pragma unroll
        for (int n = 0; n < 2; ++n) {
            const int col = nc0 + n * 16 + ln16;
            #pragma unroll
            for (int m = 0; m < 4; ++m) {
                #pragma unroll
                for (int r = 0; r < 4; ++r) {
                    const int row = m * 16 + kg * 4 + r;
                    float val = silu_f(acc[m][n][r]);
                    unsigned short hi = f2bf_trunc(val);
                    zh[row][col] = hi;
                    zl[row][col] = f2bf_trunc(val - bf2f(hi));
                }
            }
        }
    }
    __syncthreads();

    // ---------------- GEMM3 (all 8 waves): [dchi|sraw] = tanh(z2 @ [Wt|Ws] + b) ----------------
    {
        const int m3 = wv & 3;       // token quarter (16 tokens)
        const int n3 = wv >> 2;      // output-col half
        const int o  = n3 * 16 + ln16;
        const float bias3 = (o < GMAXC) ? bt[o]
                          : (o < GMAXC + NATOMC) ? bs[o - GMAXC] : 0.0f;
        f32x4 acc = (f32x4){bias3, bias3, bias3, bias3};
        const size_t wbase = (size_t)(n3 * 16 + ln16) * HDIM + kg * 8 + W3T_OFF;
        #pragma unroll
        for (int kc = 0; kc < 8; ++kc) {
            const int kk = kc * 32 + kg * 8;
            bf16x8 ah = *reinterpret_cast<const bf16x8*>(&zh[m3 * 16 + ln16][kk]);
            bf16x8 al = *reinterpret_cast<const bf16x8*>(&zl[m3 * 16 + ln16][kk]);
            const size_t wo = wbase + kc * 32;
            bf16x8 bh = *reinterpret_cast<const bf16x8*>(Wh + wo);
            acc = __builtin_amdgcn_mfma_f32_16x16x32_bf16(ah, bh, acc, 0, 0, 0);
            acc = __builtin_amdgcn_mfma_f32_16x16x32_bf16(al, bh, acc, 0, 0, 0);
            if (SPLIT) {
                bf16x8 bl = *reinterpret_cast<const bf16x8*>(Wl + wo);
                acc = __builtin_amdgcn_mfma_f32_16x16x32_bf16(ah, bl, acc, 0, 0, 0);
            }
        }
        if (o < GMAXC + NATOMC) {
            #pragma unroll
            for (int r = 0; r < 4; ++r) {
                const int tok = m3 * 16 + kg * 4 + r;
                float val = tanh_fast(acc[r]);
                if (o < GMAXC) val *= 0.5f;
                tsS[tok][o] = val;
            }
        }
    }
    __syncthreads();   // zh/zl reads complete; tsS published; zl region now dead

    // ---------------- stage X / exists wave-locally (wave w owns tokens 8w..8w+7) ----------------
    // Disjoint Xs/exS slabs per wave; FK below is same-wave -> NO barrier needed.
    {
        const int tbase = wv * 8;
        const float* Xg = X + (size_t)(tok0 + tbase) * NATOMC * 3;
        float* Xsf = &Xs[tbase][0][0];
        #pragma unroll
        for (int i = 0; i < 6; ++i) {
            const int idx = ln + i * 64;
            if (idx < 8 * NATOMC * 3) Xsf[idx] = Xg[idx];
        }
        const int* Eg = exists + (size_t)(tok0 + tbase) * NATOMC;
        uint8_t* exf = &exS[tbase][0];
        #pragma unroll
        for (int i = 0; i < 2; ++i) {
            const int idx = ln + i * 64;
            if (idx < 8 * NATOMC) exf[idx] = (uint8_t)(Eg[idx] != 0);
        }
    }
    // (no barrier: FK for wave w reads only wave-w slabs; same-wave LDS order is program order)

    // ---------------- FK: wave-local (8 tokens/wave, 8 lanes/token), NO barriers ----------------
    {
        const int t_loc = ln >> 3;              // 0..7
        const int r     = ln & 7;               // worker within token
        const int t     = wv * 8 + t_loc;       // token within tile
        const int a     = top_idx[tok0 + t];

        for (int gi = 0; gi < GMAXC; ++gi) {
            const int u  = TA[a * 8 + gi * 2 + 0];
            const int v  = TA[a * 8 + gi * 2 + 1];
            const int gc = GC[a];
            const bool axis_ok = (u >= 0) && (v >= 0) && (gi < gc);
            const int iu = u > 0 ? u : 0;
            const int iv = v > 0 ? v : 0;
            const float pux = Xs[t][iu][0], puy = Xs[t][iu][1], puz = Xs[t][iu][2];
            float ax = Xs[t][iv][0] - pux;
            float ay = Xs[t][iv][1] - puy;
            float az = Xs[t][iv][2] - puz;
            const float nrm = sqrtf(ax * ax + ay * ay + az * az);
            const float inv = 1.0f / fmaxf(nrm, 1e-8f);
            const float nx = ax * inv, ny = ay * inv, nz = az * inv;
            const float ang = axis_ok ? tsS[t][gi] : 0.0f;
            float sn, cs;
            __sincosf(ang, &sn, &cs);
            const float omc = 1.0f - cs;

            float newp[2][3];
            int   cidx[2];
            bool  wf[2];
            #pragma unroll
            for (int q = 0; q < 2; ++q) {
                const int e = r + q * 8;
                wf[q] = false; cidx[q] = 0;
                if (e < EMAXC) {
                    const int craw = AI[a * 40 + gi * 10 + e];
                    const int c = craw > 0 ? craw : 0;
                    const bool m = AM[a * 40 + gi * 10 + e] != 0;
                    const float vx = Xs[t][c][0] - pux;
                    const float vy = Xs[t][c][1] - puy;
                    const float vz = Xs[t][c][2] - puz;
                    const float dt  = vx * nx + vy * ny + vz * nz;
                    const float crx = ny * vz - nz * vy;
                    const float cry = nz * vx - nx * vz;
                    const float crz = nx * vy - ny * vx;
                    newp[q][0] = pux + vx * cs + crx * sn + nx * dt * omc;
                    newp[q][1] = puy + vy * cs + cry * sn + ny * dt * omc;
                    newp[q][2] = puz + vz * cs + crz * sn + nz * dt * omc;
                    const bool exc = exS[t][c] != 0;
                    wf[q] = m && exc;
                    cidx[q] = c;
                }
            }
            // same-wave lockstep: both gathers retire before the stores below issue
            #pragma unroll
            for (int q = 0; q < 2; ++q) {
                if (wf[q]) {
                    Xs[t][cidx[q]][0] = newp[q][0];
                    Xs[t][cidx[q]][1] = newp[q][1];
                    Xs[t][cidx[q]][2] = newp[q][2];
                }
            }
        }

        // scaling stage (reads post-torsion Xs of own token only — same wave)
        #pragma unroll
        for (int q = 0; q < 2; ++q) {
            const int e = r + q * 8;
            if (e < NATOMC) {
                const int praw = SP[a * 14 + e];
                const int p = praw > 0 ? praw : 0;
                const float ppx = Xs[t][p][0], ppy = Xs[t][p][1], ppz = Xs[t][p][2];
                const float vx = Xs[t][e][0] - ppx;
                const float vy = Xs[t][e][1] - ppy;
                const float vz = Xs[t][e][2] - ppz;
                const float sr = tsS[t][GMAXC + e];
                const float se = fminf(fmaxf(sr, -1.f), 1.f) * 0.1f;
                const float f = 1.0f + se;
                const bool w = (SM[a * 14 + e] != 0) && (exS[t][e] != 0) && (exS[t][p] != 0);
                const float ox = w ? (ppx + vx * f) : Xs[t][e][0];
                const float oy = w ? (ppy + vy * f) : Xs[t][e][1];
                const float oz = w ? (ppz + vz * f) : Xs[t][e][2];
                const size_t ob = ((size_t)(tok0 + t) * NATOMC + e) * 3;
                out[ob + 0] = ox;
                out[ob + 1] = oy;
                out[ob + 2] = oz;
            }
        }
    }
}

extern "C" void kernel_launch(void* const* d_in, const int* in_sizes, int n_in,
                              void* d_out, int out_size, void* d_ws, size_t ws_size,
                              hipStream_t stream) {
    const float* h      = (const float*)d_in[0];
    const float* probs  = (const float*)d_in[1];
    const float* X      = (const float*)d_in[2];
    const float* W1     = (const float*)d_in[3];
    const float* b1     = (const float*)d_in[4];
    const float* W2     = (const float*)d_in[5];
    const float* b2     = (const float*)d_in[6];
    const float* Wt     = (const float*)d_in[7];
    const float* bt     = (const float*)d_in[8];
    const float* Ws     = (const float*)d_in[9];
    const float* bs     = (const float*)d_in[10];
    const int*   exists = (const int*)d_in[11];
    const int*   tidx   = (const int*)d_in[12];
    const int*   TA     = (const int*)d_in[13];
    const int*   AI     = (const int*)d_in[14];
    const int*   AM     = (const int*)d_in[15];
    const int*   GC     = (const int*)d_in[16];
    const int*   SM     = (const int*)d_in[17];
    const int*   SP     = (const int*)d_in[18];
    float*       out    = (float*)d_out;
    unsigned short* ws  = (unsigned short*)d_ws;

    const int BN = in_sizes[12];          // B * N = 65536
    const int grid = BN / TM;             // 1024
    const size_t need_split = (size_t)2 * WS_ELEMS * sizeof(unsigned short);

    if (ws_size >= need_split) {
        prep_weights<true><<<(WS_ELEMS + 255) / 256, 256, 0, stream>>>(W1, W2, Wt, Ws, ws);
        fused_refiner<true><<<grid, NT, 0, stream>>>(h, probs, X, ws, b1, b2, bt, bs,
                                                     exists, tidx, TA, AI, AM, GC, SM, SP, out);
    } else {
        prep_weights<false><<<(WS_ELEMS + 255) / 256, 256, 0, stream>>>(W1, W2, Wt, Ws, ws);
        fused_refiner<false><<<grid, NT, 0, stream>>>(h, probs, X, ws, b1, b2, bt, bs,
                                                      exists, tidx, TA, AI, AM, GC, SM, SP, out);
    }
}